// Round 12
// baseline (5296.137 us; speedup 1.0000x reference)
//
#include <hip/hip_runtime.h>

// ---------------- problem constants ----------------
#define TT 100
#define NSTEP 8
__device__ __constant__ float kDT_SC = 1.0f / 24.0f;
#define HS (0.125f)

typedef float f4 __attribute__((ext_vector_type(4)));
typedef float f2 __attribute__((ext_vector_type(2)));

// ---------------- d_ws layout (floats) ----------------
#define OFF_WHH1T4   0         // [64][256][4]
#define OFF_WIH1T    65536     // [20][256]
#define OFF_WIH2AT   70656     // [8][256]
#define OFF_WIH2BT4  72704     // [64][256][4]
#define OFF_WHH2T4   138240    // [64][256][4]
#define OFF_OW1T4    203776    // [64][256][4]
#define OFF_IW1T4    269312    // [64][256][4]
#define OFF_FW1R     334848    // [64][256] row-major, zero-padded rows >= 50
#define OFF_FW2T4    351232    // [13][256][4]
#define OFF_B1C      364544    // [256] bih1+bhh1
#define OFF_B2C      364800    // [256] bih2+bhh2
#define WS_FLOATS    365056

// ---------------- LDS layout (floats) ----------------
// ycur: [2 el][2 state][272] (4 chunks of 68 = 64 data + 4 pad)
#define L_YC    0
#define L_Z     2176     // [2 el][2 state][64]
#define L_PART  2432     // [2 el][2 half][256]
#define L_XA    3456     // 2 * 28
#define L_TR    3512     // 2
#define L_RED   3514     // 16 (wv*2 + el)
#define L_FLAG  3530     // 4 uints: zA, zB, uA, uB
#define L_TOTAL 3534

__device__ __forceinline__ float fast_tanh(float v) {
    float e = __expf(2.0f * v);
    return 1.0f - 2.0f / (e + 1.0f);
}
__device__ __forceinline__ f2 vlo(f4 v) { return __builtin_shufflevector(v, v, 0, 1); }
__device__ __forceinline__ f2 vhi(f4 v) { return __builtin_shufflevector(v, v, 2, 3); }
__device__ __forceinline__ void pkfma(f2& a, f2 w, f2 h) {
    a = __builtin_elementwise_fma(w, h, a);   // v_pk_fma_f32
}
__device__ __forceinline__ float rsum2(f2 a) { return a.x + a.y; }
__device__ __forceinline__ int yi4(int jb) { return (jb >> 4) * 17 + (jb & 15); }

// 16-lane allreduce via DPP rotate-add (row_ror:1,2,4,8)
template <int CTRL>
__device__ __forceinline__ float dpp_rr_add(float v) {
    int r = __builtin_amdgcn_update_dpp(0, __float_as_int(v), CTRL, 0xF, 0xF, false);
    return v + __int_as_float(r);
}
__device__ __forceinline__ float allreduce16(float v) {
    v = dpp_rr_add<0x121>(v);
    v = dpp_rr_add<0x122>(v);
    v = dpp_rr_add<0x124>(v);
    v = dpp_rr_add<0x128>(v);
    return v;
}

// ---- LDS producer/consumer flags (workgroup scope) ----
__device__ __forceinline__ void waitFlag(unsigned int* f, unsigned int target) {
    while (__hip_atomic_load(f, __ATOMIC_ACQUIRE, __HIP_MEMORY_SCOPE_WORKGROUP) < target)
        __builtin_amdgcn_s_sleep(1);
}
__device__ __forceinline__ void incFlag(unsigned int* f, int lane) {
    if (lane == 0)
        __hip_atomic_fetch_add(f, 1u, __ATOMIC_RELEASE, __HIP_MEMORY_SCOPE_WORKGROUP);
}

// ================= setup: repack weights into d_ws =================
__global__ void codernn_setup(const float* __restrict__ Wih1, const float* __restrict__ Whh1,
                              const float* __restrict__ bih1, const float* __restrict__ bhh1,
                              const float* __restrict__ Wih2, const float* __restrict__ Whh2,
                              const float* __restrict__ bih2, const float* __restrict__ bhh2,
                              const float* __restrict__ oW1, const float* __restrict__ iW1,
                              const float* __restrict__ fW1, const float* __restrict__ fW2,
                              float* __restrict__ ws) {
    int e = blockIdx.x * 256 + threadIdx.x;
    if (e >= WS_FLOATS) return;
    float v;
    if (e < OFF_WIH1T) {                 // Whh1T4
        int q = e; int jb = q >> 10, i = (q >> 2) & 255, dj = q & 3;
        v = Whh1[i * 256 + jb * 4 + dj];
    } else if (e < OFF_WIH2AT) {         // Wih1T [20][256]
        int q = e - OFF_WIH1T; int j = q >> 8, i = q & 255;
        v = (j < 19) ? Wih1[i * 19 + j] : 0.0f;
    } else if (e < OFF_WIH2BT4) {        // Wih2aT [8][256] (insulin cols 0..4)
        int q = e - OFF_WIH2AT; int j = q >> 8, i = q & 255;
        v = (j < 5) ? Wih2[i * 261 + j] : 0.0f;
    } else if (e < OFF_WHH2T4) {         // Wih2bT4 (cols 5..260)
        int q = e - OFF_WIH2BT4; int jb = q >> 10, i = (q >> 2) & 255, dj = q & 3;
        v = Wih2[i * 261 + 5 + jb * 4 + dj];
    } else if (e < OFF_OW1T4) {          // Whh2T4
        int q = e - OFF_WHH2T4; int jb = q >> 10, i = (q >> 2) & 255, dj = q & 3;
        v = Whh2[i * 256 + jb * 4 + dj];
    } else if (e < OFF_IW1T4) {          // oW1T4
        int q = e - OFF_OW1T4; int jb = q >> 10, i = (q >> 2) & 255, dj = q & 3;
        v = oW1[i * 256 + jb * 4 + dj];
    } else if (e < OFF_FW1R) {           // iW1T4
        int q = e - OFF_IW1T4; int jb = q >> 10, i = (q >> 2) & 255, dj = q & 3;
        v = iW1[i * 256 + jb * 4 + dj];
    } else if (e < OFF_FW2T4) {          // FW1R [64][256] row-major, zero-pad k>=50
        int q = e - OFF_FW1R; int k = q >> 8, j = q & 255;
        v = (k < 50) ? fW1[k * 256 + j] : 0.0f;
    } else if (e < OFF_B1C) {            // fW2T4 [13][256][4]
        int q = e - OFF_FW2T4; int kb = q >> 10, i = (q >> 2) & 255, dk = q & 3;
        int k = kb * 4 + dk;
        v = (k < 50) ? fW2[i * 50 + k] : 0.0f;
    } else if (e < OFF_B2C) {
        int q = e - OFF_B1C; v = bih1[q] + bhh1[q];
    } else {
        int q = e - OFF_B2C; v = bih2[q] + bhh2[q];
    }
    ws[e] = v;
}

// z-phase for element EL (sh0 threads; cache[] = fW1 tile)
#define ZPHASE(EL) { \
    float pz[8]; \
    _Pragma("unroll") for (int s = 0; s < 2; ++s) { \
        const f4* ys = ycur4 + (EL) * 136 + s * 68 + (p16 >> 2) * 17 + (p16 & 3) * 4; \
        f2 P0l={0,0},P0h={0,0},P1l={0,0},P1h={0,0},P2l={0,0},P2h={0,0},P3l={0,0},P3h={0,0}; \
        _Pragma("unroll") for (int m = 0; m < 4; ++m) { \
            f4 y = ys[m]; f2 yl = vlo(y), yh = vhi(y); \
            pkfma(P0l, vlo(cache[m]), yl);      pkfma(P0h, vhi(cache[m]), yh); \
            pkfma(P1l, vlo(cache[4+m]), yl);    pkfma(P1h, vhi(cache[4+m]), yh); \
            pkfma(P2l, vlo(cache[8+m]), yl);    pkfma(P2h, vhi(cache[8+m]), yh); \
            pkfma(P3l, vlo(cache[12+m]), yl);   pkfma(P3h, vhi(cache[12+m]), yh); } \
        pz[s*4+0]=rsum2(P0l+P0h); pz[s*4+1]=rsum2(P1l+P1h); \
        pz[s*4+2]=rsum2(P2l+P2h); pz[s*4+3]=rsum2(P3l+P3h); } \
    _Pragma("unroll") for (int r = 0; r < 8; ++r) pz[r] = allreduce16(pz[r]); \
    if (p16 < 8) { const int q = p16; \
        float a0=(q&1)?pz[1]:pz[0]; float a1=(q&1)?pz[3]:pz[2]; \
        float a2=(q&1)?pz[5]:pz[4]; float a3=(q&1)?pz[7]:pz[6]; \
        float b0s=(q&2)?a1:a0; float b1s=(q&2)?a3:a2; float vsum=(q&4)?b1s:b0s; \
        float fz0=(q&1)?fb1r[1]:fb1r[0]; float fz1=(q&1)?fb1r[3]:fb1r[2]; float fb=(q&2)?fz1:fz0; \
        sm[L_Z + (EL)*128 + (q>>2)*64 + 4*kg + (q&3)] = fast_tanh(vsum + fb); } \
}

// RK4 update for element EL, stage SG (sh1 threads; cache[] = fW2 row i)
#define UPDATE(EL, SG, Y00, Y01, AC0, AC1, SCV) { \
    const f4* zva = (const f4*)(sm + L_Z + (EL) * 128); \
    const f4* zvb = zva + 16; \
    f2 AL={0,0},AH={0,0},BL={0,0},BH={0,0}; \
    _Pragma("unroll") for (int kb = 0; kb < 13; ++kb) { \
        f4 w = cache[kb]; f4 za = zva[kb], zb = zvb[kb]; \
        pkfma(AL, vlo(w), vlo(za)); pkfma(AH, vhi(w), vhi(za)); \
        pkfma(BL, vlo(w), vlo(zb)); pkfma(BH, vhi(w), vhi(zb)); } \
    float du0 = (fb2i + rsum2(AL + AH)) * (SCV); \
    float du1 = (fb2i + rsum2(BL + BH)) * (SCV); \
    float yn0, yn1; \
    if ((SG) == 0)      { AC0 = du0; AC1 = du1; yn0 = fmaf(0.5f*HS, du0, Y00); yn1 = fmaf(0.5f*HS, du1, Y01); } \
    else if ((SG) == 1) { AC0 = fmaf(2.f, du0, AC0); AC1 = fmaf(2.f, du1, AC1); yn0 = fmaf(0.5f*HS, du0, Y00); yn1 = fmaf(0.5f*HS, du1, Y01); } \
    else if ((SG) == 2) { AC0 = fmaf(2.f, du0, AC0); AC1 = fmaf(2.f, du1, AC1); yn0 = fmaf(HS, du0, Y00); yn1 = fmaf(HS, du1, Y01); } \
    else { AC0 += du0; AC1 += du1; Y00 = fmaf(HS/6.f, AC0, Y00); Y01 = fmaf(HS/6.f, AC1, Y01); yn0 = Y00; yn1 = Y01; } \
    sm[L_YC + (EL)*544 + yslot] = yn0; \
    sm[L_YC + (EL)*544 + 272 + yslot] = yn1; \
}

// ================= main kernel =================
// 256 blocks x 512 threads; 2 batch elements per block (A, B); 1 block/CU.
// sh0 waves: z-role (cache = fW1 tile). sh1 waves: update role (cache = fW2 row).
// ODE sync via LDS producer-consumer counters (no barriers inside the ODE):
//   z stage e on el X:  wait upd_done[X] >= 4e   (ycurX(e) ready; also WAR: prior z read)
//   upd stage e on el X: wait z_done[X] >= 4(e+1) (zX(e) ready; also WAR: ycur read done)
// Increments are RELEASE (drain own ds ops); waits are ACQUIRE (no read hoisting).
__global__ __launch_bounds__(512, 2) void codernn_main(
    const float* __restrict__ dt, const float* __restrict__ x,
    const float* __restrict__ ws,
    const float* __restrict__ ob1, const float* __restrict__ oW2, const float* __restrict__ ob2,
    const float* __restrict__ ib1, const float* __restrict__ iW2, const float* __restrict__ ib2,
    const float* __restrict__ fb1, const float* __restrict__ fb2,
    float* __restrict__ out) {
    __shared__ float sm[L_TOTAL];
    unsigned int* flg = (unsigned int*)&sm[L_FLAG];  // [0]=zA [1]=zB [2]=uA [3]=uB
    const int tid = threadIdx.x;
    const int i = tid & 255;
    const int sh = tid >> 8;               // wave-uniform role bit
    const int bgA = blockIdx.x * 2, bgB = bgA + 1;
    const int lane = tid & 63, wv = tid >> 6;
    const int kg = (tid >> 4) & 15;
    const int p16 = tid & 15;

    for (int idx = tid; idx < 1088; idx += 512) sm[L_YC + idx] = 0.0f;

    const float b1ci = ws[OFF_B1C + i];
    const float b2ci = ws[OFF_B2C + i];
    const float fb2i = fb2[i];
    const float W2sel = sh ? iW2[i] : oW2[i];
    const float b1sel = sh ? ib1[i] : ob1[i];
    const float ob2s = ob2[0], ib2s = ib2[0];

    const f4* Whh1T4  = (const f4*)(ws + OFF_WHH1T4);
    const float* Wih1T  = ws + OFF_WIH1T;
    const float* Wih2aT = ws + OFF_WIH2AT;
    const f4* Wih2bT4 = (const f4*)(ws + OFF_WIH2BT4);
    const f4* Whh2T4  = (const f4*)(ws + OFF_WHH2T4);
    const f4* oW1T4   = (const f4*)(ws + OFF_OW1T4);
    const f4* iW1T4   = (const f4*)(ws + OFF_IW1T4);
    const f4* ycur4   = (const f4*)(sm + L_YC);

    // role-dependent register cache (16 f4)
    f4 cache[16];
    if (sh == 0) {
        const f4* g = (const f4*)(ws + OFF_FW1R);
        #pragma unroll
        for (int r = 0; r < 4; ++r)
            #pragma unroll
            for (int m = 0; m < 4; ++m)
                cache[r * 4 + m] = g[(4 * kg + r) * 64 + p16 * 4 + m];
    } else {
        const f4* g = (const f4*)(ws + OFF_FW2T4);
        #pragma unroll
        for (int kb = 0; kb < 13; ++kb) cache[kb] = g[kb * 256 + i];
        cache[13] = (f4){0,0,0,0}; cache[14] = (f4){0,0,0,0}; cache[15] = (f4){0,0,0,0};
    }
    float fb1r[4];
    #pragma unroll
    for (int r = 0; r < 4; ++r) fb1r[r] = (4 * kg + r < 50) ? fb1[4 * kg + r] : 0.0f;

    const int yslot = (i >> 6) * 68 + (i & 63);

    float y0A0 = 0.f, y0A1 = 0.f, y0B0 = 0.f, y0B1 = 0.f;
    float accA0, accA1, accB0, accB1;
    __syncthreads();

    for (int t = 0; t < TT; ++t) {
        // ---- stage x, treat; reset ODE flags ----
        if (tid < 56) {
            int bb = tid / 28, c = tid - bb * 28;
            const float* xp = x + (bgA + bb) * (TT * 25) + t * 25;
            sm[L_XA + tid] = (c < 25) ? xp[c] : 0.0f;
            if (c == 25)
                sm[L_TR + bb] = (xp[1] > 0.f || xp[2] > 0.f || xp[3] > 0.f || xp[4] > 0.f || xp[5] > 0.f) ? 1.0f : 0.0f;
        }
        if (tid >= 60 && tid < 64) flg[tid - 60] = 0u;
        const float scA = (dt[bgA * (TT * 2) + t * 2 + 1] - dt[bgA * (TT * 2) + t * 2]) * kDT_SC;
        const float scB = (dt[bgB * (TT * 2) + t * 2 + 1] - dt[bgB * (TT * 2) + t * 2]) * kDT_SC;
        __syncthreads();

        // ---- cell1: shared weight stream, both elements; jb-range split by sh ----
        {
            float xpA = 0.f, xpB = 0.f;
            if (sh == 0) {
                xpA = fmaf(Wih1T[i], sm[L_XA + 0], b1ci);
                xpB = fmaf(Wih1T[i], sm[L_XA + 28 + 0], b1ci);
                #pragma unroll
                for (int j = 1; j < 19; ++j) {
                    float w = Wih1T[j * 256 + i];
                    xpA = fmaf(w, sm[L_XA + 6 + j], xpA);
                    xpB = fmaf(w, sm[L_XA + 28 + 6 + j], xpB);
                }
            }
            const int jb0 = sh * 32;
            f2 aLA={0,0},aHA={0,0},aLB={0,0},aHB={0,0};
            #pragma unroll 4
            for (int jb = 0; jb < 32; ++jb) {
                f4 w = Whh1T4[(jb0 + jb) * 256 + i];
                f4 hA = ycur4[yi4(jb0 + jb)];
                f4 hB = ycur4[136 + yi4(jb0 + jb)];
                pkfma(aLA, vlo(w), vlo(hA)); pkfma(aHA, vhi(w), vhi(hA));
                pkfma(aLB, vlo(w), vlo(hB)); pkfma(aHB, vhi(w), vhi(hB));
            }
            sm[L_PART + sh * 256 + i] = xpA + rsum2(aLA + aHA);
            sm[L_PART + 512 + sh * 256 + i] = xpB + rsum2(aLB + aHB);
        }
        __syncthreads();
        if (sh == 1) {
            y0A0 = y0A0 + fast_tanh(sm[L_PART + i] + sm[L_PART + 256 + i]);
            sm[L_YC + yslot] = y0A0;
            y0B0 = y0B0 + fast_tanh(sm[L_PART + 512 + i] + sm[L_PART + 768 + i]);
            sm[L_YC + 544 + yslot] = y0B0;
        }
        __syncthreads();

        // ---- cell2: sh0 = x-part + Wih2b*hc_new; sh1 = Whh2*hi_old ----
        {
            float xpA = 0.f, xpB = 0.f;
            if (sh == 0) {
                xpA = b2ci; xpB = b2ci;
                #pragma unroll
                for (int j = 0; j < 5; ++j) {
                    float w = Wih2aT[j * 256 + i];
                    xpA = fmaf(w, sm[L_XA + 1 + j], xpA);
                    xpB = fmaf(w, sm[L_XA + 28 + 1 + j], xpB);
                }
            }
            const f4* Wp = sh ? Whh2T4 : Wih2bT4;
            const int stsel = sh;
            f2 aLA={0,0},aHA={0,0},aLB={0,0},aHB={0,0};
            #pragma unroll 4
            for (int jb = 0; jb < 64; ++jb) {
                f4 w = Wp[jb * 256 + i];
                f4 hA = ycur4[stsel * 68 + yi4(jb)];
                f4 hB = ycur4[136 + stsel * 68 + yi4(jb)];
                pkfma(aLA, vlo(w), vlo(hA)); pkfma(aHA, vhi(w), vhi(hA));
                pkfma(aLB, vlo(w), vlo(hB)); pkfma(aHB, vhi(w), vhi(hB));
            }
            sm[L_PART + sh * 256 + i] = xpA + rsum2(aLA + aHA);
            sm[L_PART + 512 + sh * 256 + i] = xpB + rsum2(aLB + aHB);
        }
        __syncthreads();
        if (sh == 1) {
            y0A1 = y0A1 + fast_tanh(sm[L_PART + i] + sm[L_PART + 256 + i]);
            sm[L_YC + 272 + yslot] = y0A1;
            y0B1 = y0B1 + fast_tanh(sm[L_PART + 512 + i] + sm[L_PART + 768 + i]);
            sm[L_YC + 544 + 272 + yslot] = y0B1;
        }
        __syncthreads();   // ycur(0) + flag reset visible to all ODE waves

        // ---- ODE: flag-synced producer/consumer, no barriers ----
        if (sh == 0) {
            for (int st = 0; st < NSTEP; ++st) {
                #pragma unroll
                for (int sg = 0; sg < 4; ++sg) {
                    const unsigned int e = (unsigned int)(st * 4 + sg);
                    waitFlag(flg + 2, 4u * e);        // ycurA(e) ready (and zA readers done)
                    ZPHASE(0);
                    incFlag(flg + 0, lane);
                    waitFlag(flg + 3, 4u * e);
                    ZPHASE(1);
                    incFlag(flg + 1, lane);
                }
            }
        } else {
            for (int st = 0; st < NSTEP; ++st) {
                #pragma unroll
                for (int sg = 0; sg < 4; ++sg) {
                    const unsigned int e = (unsigned int)(st * 4 + sg);
                    waitFlag(flg + 0, 4u * (e + 1));  // zA(e) ready (and ycurA readers done)
                    UPDATE(0, sg, y0A0, y0A1, accA0, accA1, scA);
                    incFlag(flg + 2, lane);
                    waitFlag(flg + 1, 4u * (e + 1));
                    UPDATE(1, sg, y0B0, y0B1, accB0, accB1, scB);
                    incFlag(flg + 3, lane);
                }
            }
        }
        __syncthreads();   // final ycur (== h) visible

        // ---- output heads: head = sh; both elements ----
        {
            const f4* Wh = sh ? iW1T4 : oW1T4;
            const int stsel = sh;
            f2 aLA={0,0},aHA={0,0},aLB={0,0},aHB={0,0};
            #pragma unroll 4
            for (int jb = 0; jb < 64; ++jb) {
                f4 w = Wh[jb * 256 + i];
                f4 hA = ycur4[stsel * 68 + yi4(jb)];
                f4 hB = ycur4[136 + stsel * 68 + yi4(jb)];
                pkfma(aLA, vlo(w), vlo(hA)); pkfma(aHA, vhi(w), vhi(hA));
                pkfma(aLB, vlo(w), vlo(hB)); pkfma(aHB, vhi(w), vhi(hB));
            }
            float vA = W2sel * fast_tanh(b1sel + rsum2(aLA + aHA));
            float vB = W2sel * fast_tanh(b1sel + rsum2(aLB + aHB));
            #pragma unroll
            for (int off = 32; off > 0; off >>= 1) {
                vA += __shfl_xor(vA, off);
                vB += __shfl_xor(vB, off);
            }
            if (lane == 0) { sm[L_RED + wv * 2] = vA; sm[L_RED + wv * 2 + 1] = vB; }
        }
        __syncthreads();
        if (tid == 0) {
            float coA = sm[L_RED + 0] + sm[L_RED + 2] + sm[L_RED + 4] + sm[L_RED + 6] + ob2s;
            float ciA = sm[L_RED + 8] + sm[L_RED + 10] + sm[L_RED + 12] + sm[L_RED + 14] + ib2s;
            out[bgA * TT + t] = coA - sm[L_TR] * fmaxf(ciA, 0.0f);
            float coB = sm[L_RED + 1] + sm[L_RED + 3] + sm[L_RED + 5] + sm[L_RED + 7] + ob2s;
            float ciB = sm[L_RED + 9] + sm[L_RED + 11] + sm[L_RED + 13] + sm[L_RED + 15] + ib2s;
            out[bgB * TT + t] = coB - sm[L_TR + 1] * fmaxf(ciB, 0.0f);
        }
        __syncthreads();
    }
}

extern "C" void kernel_launch(void* const* d_in, const int* in_sizes, int n_in,
                              void* d_out, int out_size, void* d_ws, size_t ws_size,
                              hipStream_t stream) {
    const float* dt   = (const float*)d_in[0];
    const float* x    = (const float*)d_in[1];
    const float* Wih1 = (const float*)d_in[2];
    const float* Whh1 = (const float*)d_in[3];
    const float* bih1 = (const float*)d_in[4];
    const float* bhh1 = (const float*)d_in[5];
    const float* Wih2 = (const float*)d_in[6];
    const float* Whh2 = (const float*)d_in[7];
    const float* bih2 = (const float*)d_in[8];
    const float* bhh2 = (const float*)d_in[9];
    const float* oW1  = (const float*)d_in[10];
    const float* ob1  = (const float*)d_in[11];
    const float* oW2  = (const float*)d_in[12];
    const float* ob2  = (const float*)d_in[13];
    const float* iW1  = (const float*)d_in[14];
    const float* ib1  = (const float*)d_in[15];
    const float* iW2  = (const float*)d_in[16];
    const float* ib2  = (const float*)d_in[17];
    const float* fW1  = (const float*)d_in[18];
    const float* fb1  = (const float*)d_in[19];
    const float* fW2  = (const float*)d_in[20];
    const float* fb2  = (const float*)d_in[21];
    float* ws  = (float*)d_ws;
    float* out = (float*)d_out;

    if (ws_size < (size_t)WS_FLOATS * sizeof(float)) return;

    codernn_setup<<<WS_FLOATS / 256, 256, 0, stream>>>(Wih1, Whh1, bih1, bhh1, Wih2, Whh2,
                                                       bih2, bhh2, oW1, iW1, fW1, fW2, ws);

    codernn_main<<<256, 512, 0, stream>>>(dt, x, ws,
                                          ob1, oW2, ob2, ib1, iW2, ib2, fb1, fb2, out);
}